// Round 17
// baseline (961.905 us; speedup 1.0000x reference)
//
#include <hip/hip_runtime.h>

#define H 128
#define D 2
#define T_OBS 20
#define BATCH 16384
#define PRED 30
#define M 32          // batch rows per block (two 16-row MFMA tiles)
#define NTH 1024      // 16 waves: (wv&7)=unit group, (wv>>3)=gate pair
#define HP 136        // padded fp16 h-row stride
#define FP 132        // padded f32 row stride
#define LN_EPS 1e-5f
#define LOG2E  1.442695041f
#define LOG2E2 2.885390082f   // 2*log2e

typedef __attribute__((ext_vector_type(8))) _Float16 half8_t;
typedef __attribute__((ext_vector_type(2))) _Float16 half2_t;
typedef __attribute__((ext_vector_type(4))) float float4_t;

__device__ __forceinline__ float fast_rcp(float x){ return __builtin_amdgcn_rcpf(x); }
__device__ __forceinline__ float exp2_f(float x){ return __builtin_amdgcn_exp2f(x); }

// LDS-only barrier (R14): skip the vmcnt(0) drain of fc_out's global stores.
__device__ __forceinline__ void lds_barrier(){
  asm volatile("s_waitcnt lgkmcnt(0)\n\ts_barrier" ::: "memory");
}

// GATE-SPLIT constants: each wave owns 2 gates x 16 units. bw = 32 VGPR,
// consts 6 -> arch demand ~60 <= the 64-arch budget of a 1024-thread block
// (R7/R8: the allocator splits 64 arch + 64 accum at NTH=1024; R7's bw=64
// design spilled GBs -- this design is sized for that split).
struct PhaseConsts2 {
  half8_t bw[2][4];
  float bs[2], w0[2], w1[2];
};

__device__ __forceinline__ void load_phase2(PhaseConsts2& P, const float* __restrict__ Whh,
                                            const float* __restrict__ Wih,
                                            const float* __restrict__ bih,
                                            const float* __restrict__ bhh,
                                            int ug, int gp, int l15, int q){
#pragma unroll
  for(int gi=0; gi<2; gi++){
    const int ga = 2*gp + gi;
    const float sc = (ga==2) ? LOG2E2 : LOG2E;   // fold exp's log2e into weights
    const int n = ga*H + 16*ug + l15;
    P.bs[gi] = (bih[n] + bhh[n]) * sc;
    P.w0[gi] = Wih[n*D + 0] * sc;
    P.w1[gi] = Wih[n*D + 1] * sc;
#pragma unroll
    for(int ks=0; ks<4; ks++){
      const float* p = Whh + (size_t)n*H + ks*32 + q*8;  // B[k][n]=Whh[n][k]
      float4 a = *(const float4*)p;
      float4 b = *(const float4*)(p+4);
      half8_t f;
      f[0]=(_Float16)(a.x*sc); f[1]=(_Float16)(a.y*sc); f[2]=(_Float16)(a.z*sc); f[3]=(_Float16)(a.w*sc);
      f[4]=(_Float16)(b.x*sc); f[5]=(_Float16)(b.y*sc); f[6]=(_Float16)(b.z*sc); f[7]=(_Float16)(b.w*sc);
      P.bw[gi][ks] = f;
    }
  }
}

// Decoder fold: Wcomb = Whh + Wih*Wfc, b' = b + Wih*bfc, then *sc.
// PINNED fmaf (6-for-6 at 1 bf16 ulp across codegens: R11-R16).
__device__ __forceinline__ void load_phase2_dec(PhaseConsts2& P, const float* __restrict__ Whh,
                                                const float* __restrict__ Wih,
                                                const float* __restrict__ bih,
                                                const float* __restrict__ bhh,
                                                const float* __restrict__ Wfc,
                                                const float* __restrict__ bfc,
                                                int ug, int gp, int l15, int q){
#pragma unroll
  for(int gi=0; gi<2; gi++){
    const int ga = 2*gp + gi;
    const float sc = (ga==2) ? LOG2E2 : LOG2E;
    const int n = ga*H + 16*ug + l15;
    const float wi0 = Wih[n*D + 0];
    const float wi1 = Wih[n*D + 1];
    P.bs[gi] = fmaf(wi1, bfc[1], fmaf(wi0, bfc[0], bih[n] + bhh[n])) * sc;
    P.w0[gi] = wi0 * sc;
    P.w1[gi] = wi1 * sc;
#pragma unroll
    for(int ks=0; ks<4; ks++){
      const float* p  = Whh + (size_t)n*H + ks*32 + q*8;
      const float* f0 = Wfc + 0*H + ks*32 + q*8;
      const float* f1 = Wfc + 1*H + ks*32 + q*8;
      half8_t f;
#pragma unroll
      for(int j=0;j<8;j++){
        f[j] = (_Float16)(fmaf(wi1, f1[j], fmaf(wi0, f0[j], p[j])) * sc);
      }
      P.bw[gi][ks] = f;
    }
  }
}

// Gate-split LSTM cell step. Wave (ug,gp) computes 2 gates (2gp,2gp+1) for all
// 32 rows via MFMA, exports the other row-half's pre-acts to xch, imports the
// partner wave's (ug,1-gp) pre-acts for its own half (rows gp*16..+15), and runs
// the merged-rcp epilogue on its 4 cells. Per-cell math BITWISE IDENTICAL to R16
// (exact f32 exchange). Two LDS barriers per step.
template<bool HASX>
__device__ __forceinline__ void cell_step(_Float16 (*hsh)[M][HP], int cur,
                                          const float* __restrict__ xsrc,
                                          const PhaseConsts2& P, float (&c)[4],
                                          float (*xch)[8][64],
                                          int wv, int gp, int l15, int q, int lane, int u){
  float4_t acc[2][2];
  if constexpr (HASX){
#pragma unroll
    for(int mh=0; mh<2; mh++){
      float x0[4], x1[4];
#pragma unroll
      for(int r=0; r<4; r++){
        x0[r] = xsrc[(mh*16 + 4*q+r)*2 + 0];
        x1[r] = xsrc[(mh*16 + 4*q+r)*2 + 1];
      }
#pragma unroll
      for(int gi=0; gi<2; gi++)
#pragma unroll
        for(int r=0; r<4; r++)
          acc[mh][gi][r] = fmaf(P.w1[gi], x1[r], fmaf(P.w0[gi], x0[r], P.bs[gi]));
    }
  } else {
#pragma unroll
    for(int mh=0; mh<2; mh++)
#pragma unroll
      for(int gi=0; gi<2; gi++)
#pragma unroll
        for(int r=0; r<4; r++)
          acc[mh][gi][r] = P.bs[gi];
  }

#pragma unroll
  for(int ks=0; ks<4; ks++){
#pragma unroll
    for(int mh=0; mh<2; mh++){
      const half8_t a = *(const half8_t*)&hsh[cur][mh*16 + l15][ks*32 + q*8];
#pragma unroll
      for(int gi=0; gi<2; gi++){
        acc[mh][gi] = __builtin_amdgcn_mfma_f32_16x16x32_f16(a, P.bw[gi][ks], acc[mh][gi], 0,0,0);
      }
    }
  }

  // export the OTHER row-half's pre-activations for the partner wave
  const int omh = 1 - gp;
#pragma unroll
  for(int gi=0; gi<2; gi++)
#pragma unroll
    for(int r=0; r<4; r++)
      xch[wv][gi*4 + r][lane] = acc[omh][gi][r];
  lds_barrier();

  float pg0[4], pg1[4];   // partner's 2 gates for MY row half
#pragma unroll
  for(int r=0; r<4; r++){ pg0[r] = xch[wv^8][r][lane]; pg1[r] = xch[wv^8][4+r][lane]; }

  const int nxt = cur ^ 1;
  const int mrow = gp*16 + 4*q;
#pragma unroll
  for(int r=0; r<4; r++){
    float ai, af, ag, ao;   // wave-uniform select (gp is uniform)
    if(gp == 0){ ai = acc[0][0][r]; af = acc[0][1][r]; ag = pg0[r];        ao = pg1[r]; }
    else       { ai = pg0[r];       af = pg1[r];       ag = acc[1][0][r];  ao = acc[1][1][r]; }
    // merged-rcp epilogue (R16): 5 exp2 + 2 rcp per cell, pinned.
    const float Ei = exp2_f(-ai);
    const float Ef = exp2_f(-af);
    const float Eg = exp2_f( ag);
    const float Eo = exp2_f(-ao);
    const float tf  = 1.f + Ef;
    const float dig = (Eg + 1.f) * (1.f + Ei);
    const float m1  = (Eg - 1.f) * tf;
    const float num = fmaf(c[r], dig, m1);
    const float den = dig * tf;
    const float cc  = num * fast_rcp(den);
    c[r] = cc;
    const float ccl = fminf(cc, 30.f);
    const float Ecc = exp2_f(ccl * LOG2E2);
    const float d2  = (Ecc + 1.f) * (1.f + Eo);
    const float hv  = (Ecc - 1.f) * fast_rcp(d2);
    hsh[nxt][mrow + r][u] = (_Float16)hv;
  }
  lds_barrier();
}

// LayerNorm over 128 units for 32 rows; threads 0..511, 16 threads/row.
__device__ __forceinline__ void layernorm32(const float (*src)[FP], float (*dst)[FP],
                                            const float* __restrict__ g,
                                            const float* __restrict__ b, int tid){
  if(tid >= 512) return;
  const int m = tid >> 4, sub = tid & 15;
  float v[8];
  float s = 0.f, s2 = 0.f;
#pragma unroll
  for(int j=0;j<8;j++){ v[j] = src[m][sub*8+j]; s += v[j]; s2 = fmaf(v[j], v[j], s2); }
#pragma unroll
  for(int msk=1; msk<16; msk<<=1){ s += __shfl_xor(s, msk, 64); s2 += __shfl_xor(s2, msk, 64); }
  const float mean = s * (1.f/H);
  const float var  = fmaf(-mean, mean, s2 * (1.f/H));   // PINNED contraction
  const float inv  = rsqrtf(var + LN_EPS);
#pragma unroll
  for(int j=0;j<8;j++){
    const int u = sub*8+j;
    dst[m][u] = fmaf((v[j]-mean)*inv, g[u], b[u]);
  }
}

// Output-only FC via v_dot2_f32_f16 (threads 0..511). Writes global out ONLY.
__device__ __forceinline__ void fc_out(const _Float16 (*hb)[HP], const _Float16 (*wfch)[H],
                                       const float* __restrict__ bfcs,
                                       float* __restrict__ gout, int row0, int tid){
  if(tid >= 512) return;
  const int m = tid >> 4, d = (tid >> 3) & 1, ch = tid & 7;
  const half2_t* hp2 = (const half2_t*)&hb[m][ch*16];
  const half2_t* wp2 = (const half2_t*)&wfch[d][ch*16];
  float s = 0.f;
#pragma unroll
  for(int j=0;j<8;j++) s = __builtin_amdgcn_fdot2(hp2[j], wp2[j], s, false);
  s += __shfl_xor(s, 1, 64); s += __shfl_xor(s, 2, 64); s += __shfl_xor(s, 4, 64);
  if(ch == 0){
    gout[(size_t)(row0+m)*D + d] = s + bfcs[d];
  }
}

// Step-0 delta (threads 0..511): keeps the f32 Wfc path (feeds the recurrence).
__device__ __forceinline__ void fc_delta(const _Float16 (*hb)[HP], const float (*wfc)[H],
                                         const float* __restrict__ bfcs,
                                         const float* __restrict__ xlast,  // [M][D] contiguous
                                         float (*xb)[D], int tid){
  if(tid >= 512) return;
  const int m = tid >> 4, d = (tid >> 3) & 1, ch = tid & 7;
  const _Float16* hp = &hb[m][ch*16];
  float s = 0.f;
#pragma unroll
  for(int j=0;j<16;j++) s = fmaf((float)hp[j], wfc[d][ch*16+j], s);
  s += __shfl_xor(s, 1, 64); s += __shfl_xor(s, 2, 64); s += __shfl_xor(s, 4, 64);
  if(ch == 0){
    xb[m][d] = xlast[m*D + d] - (s + bfcs[d]);
  }
}

__global__ __launch_bounds__(NTH, 1) void traj_kernel(
    const float* __restrict__ pos, const float* __restrict__ speed,
    const float* __restrict__ Wih_pe, const float* __restrict__ Whh_pe,
    const float* __restrict__ bih_pe, const float* __restrict__ bhh_pe,
    const float* __restrict__ Wih_se, const float* __restrict__ Whh_se,
    const float* __restrict__ bih_se, const float* __restrict__ bhh_se,
    const float* __restrict__ ln_g, const float* __restrict__ ln_b,
    const float* __restrict__ Wih_sd, const float* __restrict__ Whh_sd,
    const float* __restrict__ bih_sd, const float* __restrict__ bhh_sd,
    const float* __restrict__ Wih_pd, const float* __restrict__ Whh_pd,
    const float* __restrict__ bih_pd, const float* __restrict__ bhh_pd,
    const float* __restrict__ Wfc, const float* __restrict__ bfc,
    float* __restrict__ out)
{
  __shared__ __align__(16) _Float16 hsh[2][M][HP];    // ~17.4 KB
  __shared__ float tmpf[M][FP];                        // ~16.9 KB each
  __shared__ float hpoN[M][FP];
  __shared__ float cpoN[M][FP];
  __shared__ float seqx[2][T_OBS][M][D];               // ~10.2 KB
  __shared__ float xbuf[M][D];
  __shared__ float wfcs[D][H];
  __shared__ __align__(16) _Float16 wfch[D][H];
  __shared__ float bfcs[2];
  __shared__ float xch[16][8][64];                     // 32 KB gate-exchange
  // total ~113 KB; 16 waves/block, 1 block/CU, 4 waves/SIMD

  const int tid  = threadIdx.x;
  const int lane = tid & 63;
  const int wv   = tid >> 6;       // 0..15
  const int ug   = wv & 7;         // unit group
  const int gp   = wv >> 3;        // gate pair: 0 -> {i,f}, 1 -> {g,o}
  const int q    = lane >> 4;
  const int l15  = lane & 15;
  const int row0 = blockIdx.x * M;
  const int u    = 16*ug + l15;

  // ---- stage inputs ----
  for(int idx = tid; idx < 2*T_OBS*M*D; idx += NTH){
    const int chain = idx / (T_OBS*M*D);
    const int rem   = idx % (T_OBS*M*D);
    const int t = rem / (M*D), e = rem % (M*D);
    const float* src = chain ? speed : pos;
    seqx[chain][t][e>>1][e&1] = src[(size_t)t*BATCH*D + row0*D + e];
  }
  if(tid < D*H){
    wfcs[tid>>7][tid&127] = Wfc[tid];
    wfch[tid>>7][tid&127] = (_Float16)Wfc[tid];
  }
  if(tid < 2)   bfcs[tid] = bfc[tid];
  { int* hz = (int*)&hsh[0][0][0];                    // zero buf0
    for(int idx = tid; idx < M*HP/2; idx += NTH) hz[idx] = 0; }

  PhaseConsts2 P;
  float c[4];
  load_phase2(P, Whh_pe, Wih_pe, bih_pe, bhh_pe, ug, gp, l15, q);
#pragma unroll
  for(int r=0;r<4;r++) c[r] = 0.f;
  __syncthreads();

  // ---------- phase 1: pos encoder ----------
  int cur = 0;
  for(int t=0; t<T_OBS; t++){ cell_step<true>(hsh, cur, &seqx[0][t][0][0], P, c, xch, wv, gp, l15, q, lane, u); cur ^= 1; }
  for(int idx=tid; idx<M*H; idx+=NTH){
    const int m = idx>>7, uu = idx&127;
    tmpf[m][uu] = (float)hsh[cur][m][uu];
  }
  __syncthreads();
  layernorm32(tmpf, hpoN, ln_g, ln_b, tid);
  __syncthreads();
#pragma unroll
  for(int r=0;r<4;r++) tmpf[gp*16 + 4*q+r][u] = c[r];
  __syncthreads();
  layernorm32(tmpf, cpoN, ln_g, ln_b, tid);
  __syncthreads();

  // ---------- phase 2: speed encoder ----------
  load_phase2(P, Whh_se, Wih_se, bih_se, bhh_se, ug, gp, l15, q);
#pragma unroll
  for(int r=0;r<4;r++) c[r] = 0.f;
  for(int idx=tid; idx<M*H; idx+=NTH){
    const int m = idx>>7, uu = idx&127;
    hsh[0][m][uu] = (_Float16)0.f;
  }
  cur = 0;
  __syncthreads();
  for(int t=0; t<T_OBS; t++){ cell_step<true>(hsh, cur, &seqx[1][t][0][0], P, c, xch, wv, gp, l15, q, lane, u); cur ^= 1; }
  for(int idx=tid; idx<M*H; idx+=NTH){
    const int m = idx>>7, uu = idx&127;
    tmpf[m][uu] = (float)hsh[cur][m][uu];
  }
  __syncthreads();
  layernorm32(tmpf, tmpf, ln_g, ln_b, tid);
  __syncthreads();
  // hds = LN(hsp) + LN(hpo) -> hsh[0]
  for(int idx=tid; idx<M*H; idx+=NTH){
    const int m = idx>>7, uu = idx&127;
    hsh[0][m][uu] = (_Float16)(tmpf[m][uu] + hpoN[m][uu]);
  }
  __syncthreads();
  // cds = LN(csp) + LN(cpo)
#pragma unroll
  for(int r=0;r<4;r++) tmpf[gp*16 + 4*q+r][u] = c[r];
  __syncthreads();
  layernorm32(tmpf, tmpf, ln_g, ln_b, tid);
  __syncthreads();
#pragma unroll
  for(int r=0;r<4;r++) c[r] = tmpf[gp*16 + 4*q+r][u] + cpoN[gp*16 + 4*q+r][u];

  // ---------- phase 3: speed decoder (FC folded into recurrence) ----------
  load_phase2_dec(P, Whh_sd, Wih_sd, bih_sd, bhh_sd, Wfc, bfc, ug, gp, l15, q);
  fc_delta(hsh[0], wfcs, bfcs, &seqx[1][T_OBS-1][0][0], xbuf, tid);
  __syncthreads();

  float* spd_out = out + (size_t)PRED*BATCH*D;
  cur = 0;
  cell_step<true>(hsh, cur, &xbuf[0][0], P, c, xch, wv, gp, l15, q, lane, u);
  fc_out(hsh[cur^1], wfch, bfcs, spd_out, row0, tid);
  cur ^= 1;
  for(int t=1; t<PRED; t++){
    cell_step<false>(hsh, cur, nullptr, P, c, xch, wv, gp, l15, q, lane, u);
    fc_out(hsh[cur^1], wfch, bfcs, spd_out + (size_t)t*BATCH*D, row0, tid);
    cur ^= 1;
  }
  __syncthreads();   // protect hsh buffer still being read by last fc_out before reuse

  // ---------- phase 4: pos decoder ----------
  for(int idx=tid; idx<M*H; idx+=NTH){
    const int m = idx>>7, uu = idx&127;
    hsh[0][m][uu] = (_Float16)hpoN[m][uu];
  }
#pragma unroll
  for(int r=0;r<4;r++) c[r] = cpoN[gp*16 + 4*q+r][u];
  load_phase2_dec(P, Whh_pd, Wih_pd, bih_pd, bhh_pd, Wfc, bfc, ug, gp, l15, q);
  __syncthreads();   // hsh[0] (h0 = LN(hpo)) visible
  fc_delta(hsh[0], wfcs, bfcs, &seqx[0][T_OBS-1][0][0], xbuf, tid);
  __syncthreads();   // xbuf visible

  cur = 0;
  cell_step<true>(hsh, cur, &xbuf[0][0], P, c, xch, wv, gp, l15, q, lane, u);
  fc_out(hsh[cur^1], wfch, bfcs, out, row0, tid);
  cur ^= 1;
  for(int t=1; t<PRED; t++){
    cell_step<false>(hsh, cur, nullptr, P, c, xch, wv, gp, l15, q, lane, u);
    fc_out(hsh[cur^1], wfch, bfcs, out + (size_t)t*BATCH*D, row0, tid);
    cur ^= 1;
  }
}

extern "C" void kernel_launch(void* const* d_in, const int* in_sizes, int n_in,
                              void* d_out, int out_size, void* d_ws, size_t ws_size,
                              hipStream_t stream)
{
  const float* pos    = (const float*)d_in[0];
  const float* speed  = (const float*)d_in[1];
  const float* Wih_pe = (const float*)d_in[2];
  const float* Whh_pe = (const float*)d_in[3];
  const float* bih_pe = (const float*)d_in[4];
  const float* bhh_pe = (const float*)d_in[5];
  const float* Wih_se = (const float*)d_in[6];
  const float* Whh_se = (const float*)d_in[7];
  const float* bih_se = (const float*)d_in[8];
  const float* bhh_se = (const float*)d_in[9];
  const float* ln_g   = (const float*)d_in[10];
  const float* ln_b   = (const float*)d_in[11];
  const float* Wih_sd = (const float*)d_in[12];
  const float* Whh_sd = (const float*)d_in[13];
  const float* bih_sd = (const float*)d_in[14];
  const float* bhh_sd = (const float*)d_in[15];
  const float* Wih_pd = (const float*)d_in[16];
  const float* Whh_pd = (const float*)d_in[17];
  const float* bih_pd = (const float*)d_in[18];
  const float* bhh_pd = (const float*)d_in[19];
  const float* Wfc    = (const float*)d_in[20];
  const float* bfc    = (const float*)d_in[21];

  traj_kernel<<<BATCH/M, NTH, 0, stream>>>(
      pos, speed, Wih_pe, Whh_pe, bih_pe, bhh_pe,
      Wih_se, Whh_se, bih_se, bhh_se, ln_g, ln_b,
      Wih_sd, Whh_sd, bih_sd, bhh_sd, Wih_pd, Whh_pd, bih_pd, bhh_pd,
      Wfc, bfc, (float*)d_out);
}

// Round 18
// 467.693 us; speedup vs baseline: 2.0567x; 2.0567x over previous
//
#include <hip/hip_runtime.h>

#define H 128
#define D 2
#define T_OBS 20
#define BATCH 16384
#define PRED 30
#define M 64          // batch rows per block (four 16-row MFMA tiles) -> grid 256 = 1 round
#define NTH 512       // 8 waves; wave wv owns units 16*wv .. 16*wv+15 (all 4 gates)
#define HP 136        // padded fp16 h-row stride
#define FP 132        // padded f32 row stride
#define LN_EPS 1e-5f
#define LOG2E  1.442695041f
#define LOG2E2 2.885390082f   // 2*log2e

typedef __attribute__((ext_vector_type(8))) _Float16 half8_t;
typedef __attribute__((ext_vector_type(2))) _Float16 half2_t;
typedef __attribute__((ext_vector_type(4))) float float4_t;

__device__ __forceinline__ float fast_rcp(float x){ return __builtin_amdgcn_rcpf(x); }
__device__ __forceinline__ float exp2_f(float x){ return __builtin_amdgcn_exp2f(x); }

// LDS-only barrier (R14): skip the vmcnt(0) drain of fc_out's global stores.
__device__ __forceinline__ void lds_barrier(){
  asm volatile("s_waitcnt lgkmcnt(0)\n\ts_barrier" ::: "memory");
}

// Per-phase per-wave constants: bw 64 VGPR + consts 12; acc 64 AGPR (M=64).
// (512,2) is the ONLY non-spilling envelope (R7/R8/R11/R12/R13/R17:
// every 1024-thread or forced-cap variant spilled GBs).
struct PhaseConsts {
  half8_t bw[4][4];
  float bs[4], w0[4], w1[4];
};

__device__ __forceinline__ void load_phase(PhaseConsts& P, const float* __restrict__ Whh,
                                           const float* __restrict__ Wih,
                                           const float* __restrict__ bih,
                                           const float* __restrict__ bhh,
                                           int wv, int l15, int q){
#pragma unroll
  for(int g=0; g<4; g++){
    const float sc = (g==2) ? LOG2E2 : LOG2E;   // fold exp's log2e into weights
    const int n = g*H + 16*wv + l15;
    P.bs[g] = (bih[n] + bhh[n]) * sc;
    P.w0[g] = Wih[n*D + 0] * sc;
    P.w1[g] = Wih[n*D + 1] * sc;
#pragma unroll
    for(int ks=0; ks<4; ks++){
      const float* p = Whh + (size_t)n*H + ks*32 + q*8;  // B[k][n]=Whh[n][k]
      float4 a = *(const float4*)p;
      float4 b = *(const float4*)(p+4);
      half8_t f;
      f[0]=(_Float16)(a.x*sc); f[1]=(_Float16)(a.y*sc); f[2]=(_Float16)(a.z*sc); f[3]=(_Float16)(a.w*sc);
      f[4]=(_Float16)(b.x*sc); f[5]=(_Float16)(b.y*sc); f[6]=(_Float16)(b.z*sc); f[7]=(_Float16)(b.w*sc);
      P.bw[g][ks] = f;
    }
  }
}

// Decoder fold: Wcomb = Whh + Wih*Wfc, b' = b + Wih*bfc, then *sc.
// PINNED fmaf (6-for-6 at 1 bf16 ulp across codegens: R11-R16).
__device__ __forceinline__ void load_phase_dec(PhaseConsts& P, const float* __restrict__ Whh,
                                               const float* __restrict__ Wih,
                                               const float* __restrict__ bih,
                                               const float* __restrict__ bhh,
                                               const float* __restrict__ Wfc,
                                               const float* __restrict__ bfc,
                                               int wv, int l15, int q){
#pragma unroll
  for(int g=0; g<4; g++){
    const float sc = (g==2) ? LOG2E2 : LOG2E;
    const int n = g*H + 16*wv + l15;
    const float wi0 = Wih[n*D + 0];
    const float wi1 = Wih[n*D + 1];
    P.bs[g] = fmaf(wi1, bfc[1], fmaf(wi0, bfc[0], bih[n] + bhh[n])) * sc;
    P.w0[g] = wi0 * sc;
    P.w1[g] = wi1 * sc;
#pragma unroll
    for(int ks=0; ks<4; ks++){
      const float* p  = Whh + (size_t)n*H + ks*32 + q*8;
      const float* f0 = Wfc + 0*H + ks*32 + q*8;
      const float* f1 = Wfc + 1*H + ks*32 + q*8;
      half8_t f;
#pragma unroll
      for(int j=0;j<8;j++){
        f[j] = (_Float16)(fmaf(wi1, f1[j], fmaf(wi0, f0[j], p[j])) * sc);
      }
      P.bw[g][ks] = f;
    }
  }
}

// One LSTM cell step for 64 rows (four 16-row m-halves, independent accumulators).
// h read from hsh[cur] (single fp16 plane), x from xsrc[64][2] (only when HASX),
// new h written to hsh[cur^1]. c per-lane fp32. One LDS-only barrier.
// Per-row arithmetic BITWISE IDENTICAL to R16 (rows are independent in MFMA).
template<bool HASX>
__device__ __forceinline__ void cell_step(_Float16 (*hsh)[M][HP], int cur,
                                          const float* __restrict__ xsrc,
                                          const PhaseConsts& P, float (&c)[4][4],
                                          int wv, int l15, int q){
  float4_t acc[4][4];
  if constexpr (HASX){
#pragma unroll
    for(int mh=0; mh<4; mh++){
      float x0[4], x1[4];
#pragma unroll
      for(int r=0; r<4; r++){
        x0[r] = xsrc[(mh*16 + 4*q+r)*2 + 0];
        x1[r] = xsrc[(mh*16 + 4*q+r)*2 + 1];
      }
#pragma unroll
      for(int g=0; g<4; g++)
#pragma unroll
        for(int r=0; r<4; r++)
          acc[mh][g][r] = fmaf(P.w1[g], x1[r], fmaf(P.w0[g], x0[r], P.bs[g]));
    }
  } else {
#pragma unroll
    for(int mh=0; mh<4; mh++)
#pragma unroll
      for(int g=0; g<4; g++)
#pragma unroll
        for(int r=0; r<4; r++)
          acc[mh][g][r] = P.bs[g];
  }

#pragma unroll
  for(int ks=0; ks<4; ks++){
#pragma unroll
    for(int mh=0; mh<4; mh++){
      const half8_t a = *(const half8_t*)&hsh[cur][mh*16 + l15][ks*32 + q*8];
#pragma unroll
      for(int g=0; g<4; g++){
        acc[mh][g] = __builtin_amdgcn_mfma_f32_16x16x32_f16(a, P.bw[g][ks], acc[mh][g], 0,0,0);
      }
    }
  }
  const int nxt = cur ^ 1;
  const int u = 16*wv + l15;
#pragma unroll
  for(int mh=0; mh<4; mh++){
#pragma unroll
    for(int r=0; r<4; r++){
      // merged-rcp epilogue (R16): 5 exp2 + 2 rcp per cell, pinned.
      const float Ei = exp2_f(-acc[mh][0][r]);
      const float Ef = exp2_f(-acc[mh][1][r]);
      const float Eg = exp2_f( acc[mh][2][r]);
      const float Eo = exp2_f(-acc[mh][3][r]);
      const float tf  = 1.f + Ef;
      const float dig = (Eg + 1.f) * (1.f + Ei);
      const float m1  = (Eg - 1.f) * tf;
      const float num = fmaf(c[mh][r], dig, m1);
      const float den = dig * tf;
      const float cc  = num * fast_rcp(den);
      c[mh][r] = cc;
      const float ccl = fminf(cc, 30.f);
      const float Ecc = exp2_f(ccl * LOG2E2);
      const float d2  = (Ecc + 1.f) * (1.f + Eo);
      const float hv  = (Ecc - 1.f) * fast_rcp(d2);
      const int m = mh*16 + 4*q + r;
      hsh[nxt][m][u] = (_Float16)hv;
    }
  }
  lds_barrier();
}

// LayerNorm over 128 units for 64 rows; 512 threads = 16/row over two 32-row
// halves. Per-row arithmetic IDENTICAL to R16's 16-lane tree.
__device__ __forceinline__ void layernorm64(const float (*src)[FP], float (*dst)[FP],
                                            const float* __restrict__ g,
                                            const float* __restrict__ b, int tid){
  const int mb = tid >> 4, sub = tid & 15;
#pragma unroll
  for(int half=0; half<2; half++){
    const int m = half*32 + mb;
    float v[8];
    float s = 0.f, s2 = 0.f;
#pragma unroll
    for(int j=0;j<8;j++){ v[j] = src[m][sub*8+j]; s += v[j]; s2 = fmaf(v[j], v[j], s2); }
#pragma unroll
    for(int msk=1; msk<16; msk<<=1){ s += __shfl_xor(s, msk, 64); s2 += __shfl_xor(s2, msk, 64); }
    const float mean = s * (1.f/H);
    const float var  = fmaf(-mean, mean, s2 * (1.f/H));   // PINNED contraction
    const float inv  = rsqrtf(var + LN_EPS);
#pragma unroll
    for(int j=0;j<8;j++){
      const int u = sub*8+j;
      dst[m][u] = fmaf((v[j]-mean)*inv, g[u], b[u]);
    }
  }
}

// Output-only FC via v_dot2_f32_f16 for 64 rows (two 32-row halves).
// Writes global out ONLY. No barrier needed: hb rewritten two cell-steps later.
__device__ __forceinline__ void fc_out(const _Float16 (*hb)[HP], const _Float16 (*wfch)[H],
                                       const float* __restrict__ bfcs,
                                       float* __restrict__ gout, int row0, int tid){
  const int mb = tid >> 4, d = (tid >> 3) & 1, ch = tid & 7;
#pragma unroll
  for(int half=0; half<2; half++){
    const int m = half*32 + mb;
    const half2_t* hp2 = (const half2_t*)&hb[m][ch*16];
    const half2_t* wp2 = (const half2_t*)&wfch[d][ch*16];
    float s = 0.f;
#pragma unroll
    for(int j=0;j<8;j++) s = __builtin_amdgcn_fdot2(hp2[j], wp2[j], s, false);
    s += __shfl_xor(s, 1, 64); s += __shfl_xor(s, 2, 64); s += __shfl_xor(s, 4, 64);
    if(ch == 0){
      gout[(size_t)(row0+m)*D + d] = s + bfcs[d];
    }
  }
}

// Step-0 delta for 64 rows: keeps the f32 Wfc path (feeds the recurrence).
__device__ __forceinline__ void fc_delta(const _Float16 (*hb)[HP], const float (*wfc)[H],
                                         const float* __restrict__ bfcs,
                                         const float* __restrict__ xlast,  // [M][D] contiguous
                                         float (*xb)[D], int tid){
  const int mb = tid >> 4, d = (tid >> 3) & 1, ch = tid & 7;
#pragma unroll
  for(int half=0; half<2; half++){
    const int m = half*32 + mb;
    const _Float16* hp = &hb[m][ch*16];
    float s = 0.f;
#pragma unroll
    for(int j=0;j<16;j++) s = fmaf((float)hp[j], wfc[d][ch*16+j], s);
    s += __shfl_xor(s, 1, 64); s += __shfl_xor(s, 2, 64); s += __shfl_xor(s, 4, 64);
    if(ch == 0){
      xb[m][d] = xlast[m*D + d] - (s + bfcs[d]);
    }
  }
}

__global__ __launch_bounds__(NTH, 2) void traj_kernel(
    const float* __restrict__ pos, const float* __restrict__ speed,
    const float* __restrict__ Wih_pe, const float* __restrict__ Whh_pe,
    const float* __restrict__ bih_pe, const float* __restrict__ bhh_pe,
    const float* __restrict__ Wih_se, const float* __restrict__ Whh_se,
    const float* __restrict__ bih_se, const float* __restrict__ bhh_se,
    const float* __restrict__ ln_g, const float* __restrict__ ln_b,
    const float* __restrict__ Wih_sd, const float* __restrict__ Whh_sd,
    const float* __restrict__ bih_sd, const float* __restrict__ bhh_sd,
    const float* __restrict__ Wih_pd, const float* __restrict__ Whh_pd,
    const float* __restrict__ bih_pd, const float* __restrict__ bhh_pd,
    const float* __restrict__ Wfc, const float* __restrict__ bfc,
    float* __restrict__ out)
{
  __shared__ __align__(16) _Float16 hsh[2][M][HP];    // 34.8 KB
  __shared__ float tmpf[M][FP];                        // 33.8 KB each
  __shared__ float hpoN[M][FP];
  __shared__ float cpoN[M][FP];
  __shared__ float seqx[2][T_OBS][M][D];               // 20.5 KB
  __shared__ float xbuf[M][D];
  __shared__ float wfcs[D][H];
  __shared__ __align__(16) _Float16 wfch[D][H];
  __shared__ float bfcs[2];
  // total ~158.7 KB <= 160 KB; grid 256 = 1 block/CU = ONE sequential round

  const int tid  = threadIdx.x;
  const int lane = tid & 63;
  const int wv   = tid >> 6;       // 0..7 -> unit group
  const int q    = lane >> 4;
  const int l15  = lane & 15;
  const int row0 = blockIdx.x * M;
  const int u    = 16*wv + l15;

  // ---- stage inputs ----
  for(int idx = tid; idx < 2*T_OBS*M*D; idx += NTH){
    const int chain = idx / (T_OBS*M*D);
    const int rem   = idx % (T_OBS*M*D);
    const int t = rem / (M*D), e = rem % (M*D);
    const float* src = chain ? speed : pos;
    seqx[chain][t][e>>1][e&1] = src[(size_t)t*BATCH*D + row0*D + e];
  }
  if(tid < D*H){
    wfcs[tid>>7][tid&127] = Wfc[tid];
    wfch[tid>>7][tid&127] = (_Float16)Wfc[tid];
  }
  if(tid < 2)   bfcs[tid] = bfc[tid];
  { int* hz = (int*)&hsh[0][0][0];                    // zero buf0 (M*HP fp16 = 4352 ints)
    for(int idx = tid; idx < M*HP/2; idx += NTH) hz[idx] = 0; }

  PhaseConsts P;
  float c[4][4];
  load_phase(P, Whh_pe, Wih_pe, bih_pe, bhh_pe, wv, l15, q);
#pragma unroll
  for(int mh=0;mh<4;mh++)
#pragma unroll
    for(int r=0;r<4;r++) c[mh][r] = 0.f;
  __syncthreads();

  // ---------- phase 1: pos encoder ----------
  int cur = 0;
  for(int t=0; t<T_OBS; t++){ cell_step<true>(hsh, cur, &seqx[0][t][0][0], P, c, wv, l15, q); cur ^= 1; }
  for(int idx=tid; idx<M*H; idx+=NTH){
    const int m = idx>>7, uu = idx&127;
    tmpf[m][uu] = (float)hsh[cur][m][uu];
  }
  __syncthreads();
  layernorm64(tmpf, hpoN, ln_g, ln_b, tid);
  __syncthreads();
#pragma unroll
  for(int mh=0;mh<4;mh++)
#pragma unroll
    for(int r=0;r<4;r++) tmpf[mh*16 + 4*q+r][u] = c[mh][r];
  __syncthreads();
  layernorm64(tmpf, cpoN, ln_g, ln_b, tid);
  __syncthreads();

  // ---------- phase 2: speed encoder ----------
  load_phase(P, Whh_se, Wih_se, bih_se, bhh_se, wv, l15, q);
#pragma unroll
  for(int mh=0;mh<4;mh++)
#pragma unroll
    for(int r=0;r<4;r++) c[mh][r] = 0.f;
  for(int idx=tid; idx<M*H; idx+=NTH){
    const int m = idx>>7, uu = idx&127;
    hsh[0][m][uu] = (_Float16)0.f;
  }
  cur = 0;
  __syncthreads();
  for(int t=0; t<T_OBS; t++){ cell_step<true>(hsh, cur, &seqx[1][t][0][0], P, c, wv, l15, q); cur ^= 1; }
  for(int idx=tid; idx<M*H; idx+=NTH){
    const int m = idx>>7, uu = idx&127;
    tmpf[m][uu] = (float)hsh[cur][m][uu];
  }
  __syncthreads();
  layernorm64(tmpf, tmpf, ln_g, ln_b, tid);
  __syncthreads();
  // hds = LN(hsp) + LN(hpo) -> hsh[0]
  for(int idx=tid; idx<M*H; idx+=NTH){
    const int m = idx>>7, uu = idx&127;
    hsh[0][m][uu] = (_Float16)(tmpf[m][uu] + hpoN[m][uu]);
  }
  __syncthreads();
  // cds = LN(csp) + LN(cpo)
#pragma unroll
  for(int mh=0;mh<4;mh++)
#pragma unroll
    for(int r=0;r<4;r++) tmpf[mh*16 + 4*q+r][u] = c[mh][r];
  __syncthreads();
  layernorm64(tmpf, tmpf, ln_g, ln_b, tid);
  __syncthreads();
#pragma unroll
  for(int mh=0;mh<4;mh++)
#pragma unroll
    for(int r=0;r<4;r++) c[mh][r] = tmpf[mh*16 + 4*q+r][u] + cpoN[mh*16 + 4*q+r][u];

  // ---------- phase 3: speed decoder (FC folded into recurrence) ----------
  load_phase_dec(P, Whh_sd, Wih_sd, bih_sd, bhh_sd, Wfc, bfc, wv, l15, q);
  fc_delta(hsh[0], wfcs, bfcs, &seqx[1][T_OBS-1][0][0], xbuf, tid);
  __syncthreads();

  float* spd_out = out + (size_t)PRED*BATCH*D;
  cur = 0;
  cell_step<true>(hsh, cur, &xbuf[0][0], P, c, wv, l15, q);
  fc_out(hsh[cur^1], wfch, bfcs, spd_out, row0, tid);
  cur ^= 1;
  for(int t=1; t<PRED; t++){
    cell_step<false>(hsh, cur, nullptr, P, c, wv, l15, q);
    fc_out(hsh[cur^1], wfch, bfcs, spd_out + (size_t)t*BATCH*D, row0, tid);
    cur ^= 1;
  }
  __syncthreads();   // protect hsh buffer still being read by last fc_out before reuse

  // ---------- phase 4: pos decoder ----------
  for(int idx=tid; idx<M*H; idx+=NTH){
    const int m = idx>>7, uu = idx&127;
    hsh[0][m][uu] = (_Float16)hpoN[m][uu];
  }
#pragma unroll
  for(int mh=0;mh<4;mh++)
#pragma unroll
    for(int r=0;r<4;r++) c[mh][r] = cpoN[mh*16 + 4*q+r][u];
  load_phase_dec(P, Whh_pd, Wih_pd, bih_pd, bhh_pd, Wfc, bfc, wv, l15, q);
  __syncthreads();   // hsh[0] (h0 = LN(hpo)) visible
  fc_delta(hsh[0], wfcs, bfcs, &seqx[0][T_OBS-1][0][0], xbuf, tid);
  __syncthreads();   // xbuf visible

  cur = 0;
  cell_step<true>(hsh, cur, &xbuf[0][0], P, c, wv, l15, q);
  fc_out(hsh[cur^1], wfch, bfcs, out, row0, tid);
  cur ^= 1;
  for(int t=1; t<PRED; t++){
    cell_step<false>(hsh, cur, nullptr, P, c, wv, l15, q);
    fc_out(hsh[cur^1], wfch, bfcs, out + (size_t)t*BATCH*D, row0, tid);
    cur ^= 1;
  }
}

extern "C" void kernel_launch(void* const* d_in, const int* in_sizes, int n_in,
                              void* d_out, int out_size, void* d_ws, size_t ws_size,
                              hipStream_t stream)
{
  const float* pos    = (const float*)d_in[0];
  const float* speed  = (const float*)d_in[1];
  const float* Wih_pe = (const float*)d_in[2];
  const float* Whh_pe = (const float*)d_in[3];
  const float* bih_pe = (const float*)d_in[4];
  const float* bhh_pe = (const float*)d_in[5];
  const float* Wih_se = (const float*)d_in[6];
  const float* Whh_se = (const float*)d_in[7];
  const float* bih_se = (const float*)d_in[8];
  const float* bhh_se = (const float*)d_in[9];
  const float* ln_g   = (const float*)d_in[10];
  const float* ln_b   = (const float*)d_in[11];
  const float* Wih_sd = (const float*)d_in[12];
  const float* Whh_sd = (const float*)d_in[13];
  const float* bih_sd = (const float*)d_in[14];
  const float* bhh_sd = (const float*)d_in[15];
  const float* Wih_pd = (const float*)d_in[16];
  const float* Whh_pd = (const float*)d_in[17];
  const float* bih_pd = (const float*)d_in[18];
  const float* bhh_pd = (const float*)d_in[19];
  const float* Wfc    = (const float*)d_in[20];
  const float* bfc    = (const float*)d_in[21];

  traj_kernel<<<BATCH/M, NTH, 0, stream>>>(
      pos, speed, Wih_pe, Whh_pe, bih_pe, bhh_pe,
      Wih_se, Whh_se, bih_se, bhh_se, ln_g, ln_b,
      Wih_sd, Whh_sd, bih_sd, bhh_sd, Wih_pd, Whh_pd, bih_pd, bhh_pd,
      Wfc, bfc, (float*)d_out);
}